// Round 14
// baseline (291.652 us; speedup 1.0000x reference)
//
#include <hip/hip_runtime.h>
#include <hip/hip_bf16.h>

typedef __bf16 bf16_t;
typedef __bf16 bf16x8 __attribute__((ext_vector_type(8)));
typedef __bf16 bf16x4 __attribute__((ext_vector_type(4)));
typedef float f32x4 __attribute__((ext_vector_type(4)));

#define B_ 2
#define L_ 1024
#define D_ 1024
#define H_ 16
#define HD_ 64

// DPP rotate-reduce helper: fmax with lane (i+N)%16 within each 16-lane row.
template <int CTRL>
static __device__ __forceinline__ float dpp_fmax(float v) {
    const int t = __builtin_amdgcn_update_dpp(0, __float_as_int(v), CTRL,
                                              0xF, 0xF, true);
    return fmaxf(v, __int_as_float(t));
}

// ---------------------------------------------------------------------------
// Fused prep: x-cast (blocks 0..2047), W casts (2048..6143), E shift+cast
// (6144..6655).  (unchanged, passing)
// ---------------------------------------------------------------------------
__global__ __launch_bounds__(256) void prep_kernel(
    const float* __restrict__ x,
    const float* __restrict__ Wq, const float* __restrict__ Wk,
    const float* __restrict__ Wv, const float* __restrict__ Wo,
    const float* __restrict__ E,
    bf16_t* __restrict__ xb,
    bf16_t* __restrict__ Wqb, bf16_t* __restrict__ Wkb,
    bf16_t* __restrict__ Wvb, bf16_t* __restrict__ Wob,
    bf16_t* __restrict__ Eb) {
    const int bid = blockIdx.x;
    if (bid < 6144) {
        const float* src;
        bf16_t* dst;
        int i;
        if (bid < 2048) {
            src = x; dst = xb; i = bid * 256 + threadIdx.x;
        } else {
            const int z = (bid - 2048) >> 10;
            src = (z == 0) ? Wq : (z == 1) ? Wk : (z == 2) ? Wv : Wo;
            dst = (z == 0) ? Wqb : (z == 1) ? Wkb : (z == 2) ? Wvb : Wob;
            i = ((bid - 2048) & 1023) * 256 + threadIdx.x;
        }
        const float4 v = ((const float4*)src)[i];
        bf16x4 o;
        o[0] = (bf16_t)v.x; o[1] = (bf16_t)v.y;
        o[2] = (bf16_t)v.z; o[3] = (bf16_t)v.w;
        ((bf16x4*)dst)[i] = o;
    } else {
        const int idx = (bid - 6144) * 256 + threadIdx.x;
        if (idx < 64) Eb[idx] = (bf16_t)0.f;
        if (idx < 2047 * 64) Eb[64 + idx] = (bf16_t)E[idx];
    }
}

// ---------------------------------------------------------------------------
// r14: 128x64-tile GEMM, BK=64, register double-buffered staging.
// __launch_bounds__(256, 2): min 2 waves/EU -> VGPR cap 256. r13's default
// heuristic capped at 48 VGPR and SPILLED the accumulators to scratch
// (WRITE_SIZE 8 MB -> 295 MB, qkv 38 -> 96 us). ~120 VGPRs live here.
// ---------------------------------------------------------------------------
__global__ __launch_bounds__(256, 2) void qkv_gemm_kernel(
    const bf16_t* __restrict__ xb,
    const bf16_t* __restrict__ Wqb, const bf16_t* __restrict__ Wkb,
    const bf16_t* __restrict__ Wvb,
    const float* __restrict__ bq, const float* __restrict__ bk2,
    const float* __restrict__ bv2,
    bf16_t* __restrict__ qbh, bf16_t* __restrict__ kbh,
    bf16_t* __restrict__ vtb) {
    constexpr int K = D_;
    __shared__ __align__(16) bf16_t As[128][72];
    __shared__ __align__(16) bf16_t Bs[64][72];

    const int z = blockIdx.z;
    const bf16_t* W = (z == 0) ? Wqb : (z == 1) ? Wkb : Wvb;
    const float* bias = (z == 0) ? bq : (z == 1) ? bk2 : bv2;
    const float alpha = (z == 0) ? 0.125f : 1.0f;

    const int tid = threadIdx.x;
    const int m0 = blockIdx.y * 128;
    const int n0 = blockIdx.x * 64;
    const int w = tid >> 6;
    const int lane = tid & 63;
    const int n = lane & 15;
    const int q4 = lane >> 4;
    const int r0 = tid >> 3;          // 0..31
    const int c8 = (tid & 7) << 3;    // 0..56

    f32x4 acc[2][4] = {};

    uint4 pA[4], pB[2];
#pragma unroll
    for (int i = 0; i < 4; ++i)
        pA[i] = *(const uint4*)&xb[(size_t)(m0 + r0 + 32 * i) * K + c8];
#pragma unroll
    for (int i = 0; i < 2; ++i)
        pB[i] = *(const uint4*)&W[(size_t)(n0 + r0 + 32 * i) * K + c8];

    for (int k0 = 0; k0 < K; k0 += 64) {
#pragma unroll
        for (int i = 0; i < 4; ++i) *(uint4*)&As[r0 + 32 * i][c8] = pA[i];
#pragma unroll
        for (int i = 0; i < 2; ++i) *(uint4*)&Bs[r0 + 32 * i][c8] = pB[i];
        const int kn = (k0 + 64 < K) ? k0 + 64 : k0;
#pragma unroll
        for (int i = 0; i < 4; ++i)
            pA[i] = *(const uint4*)&xb[(size_t)(m0 + r0 + 32 * i) * K + kn + c8];
#pragma unroll
        for (int i = 0; i < 2; ++i)
            pB[i] = *(const uint4*)&W[(size_t)(n0 + r0 + 32 * i) * K + kn + c8];
        __syncthreads();

#pragma unroll
        for (int kc = 0; kc < 2; ++kc) {
            bf16x8 af[2], bfr[4];
#pragma unroll
            for (int m = 0; m < 2; ++m)
                af[m] = *(const bf16x8*)&As[w * 32 + 16 * m + n][kc * 32 + 8 * q4];
#pragma unroll
            for (int u = 0; u < 4; ++u)
                bfr[u] = *(const bf16x8*)&Bs[16 * u + n][kc * 32 + 8 * q4];
#pragma unroll
            for (int m = 0; m < 2; ++m)
#pragma unroll
                for (int u = 0; u < 4; ++u)
                    acc[m][u] = __builtin_amdgcn_mfma_f32_16x16x32_bf16(
                        af[m], bfr[u], acc[m][u], 0, 0, 0);
        }
        __syncthreads();
    }

#pragma unroll
    for (int m = 0; m < 2; ++m) {
#pragma unroll
        for (int u = 0; u < 4; ++u) {
            const int col = n0 + 16 * u + n;
            const float bvv = bias[col];
            const int h = col >> 6, d = col & 63;
            if (z < 2) {
                bf16_t* outp = z ? kbh : qbh;
#pragma unroll
                for (int r = 0; r < 4; ++r) {
                    const int row = m0 + 32 * w + 16 * m + 4 * q4 + r;
                    const int b = row >> 10, i = row & 1023;
                    outp[((size_t)((b * H_ + h) * L_ + i)) * HD_ + d] =
                        (bf16_t)((acc[m][u][r] + bvv) * alpha);
                }
            } else {
                const int row0 = m0 + 32 * w + 16 * m + 4 * q4;  // %4 == 0
                const int b = row0 >> 10, i = row0 & 1023;
                bf16x4 pk;
#pragma unroll
                for (int r = 0; r < 4; ++r) pk[r] = (bf16_t)(acc[m][u][r] + bvv);
                *(bf16x4*)&vtb[((size_t)((b * H_ + h) * HD_ + d)) * L_ + i] = pk;
            }
        }
    }
}

// ---------------------------------------------------------------------------
// Wo GEMM, 128x64 tile, BK=64, register dbuf, fp32 out. Same VGPR-cap fix.
// ---------------------------------------------------------------------------
__global__ __launch_bounds__(256, 2) void out_gemm_kernel(
    const bf16_t* __restrict__ A, const bf16_t* __restrict__ W,
    const float* __restrict__ bias, float* __restrict__ outF) {
    constexpr int K = D_;
    __shared__ __align__(16) bf16_t As[128][72];
    __shared__ __align__(16) bf16_t Bs[64][72];

    const int tid = threadIdx.x;
    const int m0 = blockIdx.y * 128;
    const int n0 = blockIdx.x * 64;
    const int w = tid >> 6;
    const int lane = tid & 63;
    const int n = lane & 15;
    const int q4 = lane >> 4;
    const int r0 = tid >> 3;
    const int c8 = (tid & 7) << 3;

    f32x4 acc[2][4] = {};

    uint4 pA[4], pB[2];
#pragma unroll
    for (int i = 0; i < 4; ++i)
        pA[i] = *(const uint4*)&A[(size_t)(m0 + r0 + 32 * i) * K + c8];
#pragma unroll
    for (int i = 0; i < 2; ++i)
        pB[i] = *(const uint4*)&W[(size_t)(n0 + r0 + 32 * i) * K + c8];

    for (int k0 = 0; k0 < K; k0 += 64) {
#pragma unroll
        for (int i = 0; i < 4; ++i) *(uint4*)&As[r0 + 32 * i][c8] = pA[i];
#pragma unroll
        for (int i = 0; i < 2; ++i) *(uint4*)&Bs[r0 + 32 * i][c8] = pB[i];
        const int kn = (k0 + 64 < K) ? k0 + 64 : k0;
#pragma unroll
        for (int i = 0; i < 4; ++i)
            pA[i] = *(const uint4*)&A[(size_t)(m0 + r0 + 32 * i) * K + kn + c8];
#pragma unroll
        for (int i = 0; i < 2; ++i)
            pB[i] = *(const uint4*)&W[(size_t)(n0 + r0 + 32 * i) * K + kn + c8];
        __syncthreads();

#pragma unroll
        for (int kc = 0; kc < 2; ++kc) {
            bf16x8 af[2], bfr[4];
#pragma unroll
            for (int m = 0; m < 2; ++m)
                af[m] = *(const bf16x8*)&As[w * 32 + 16 * m + n][kc * 32 + 8 * q4];
#pragma unroll
            for (int u = 0; u < 4; ++u)
                bfr[u] = *(const bf16x8*)&Bs[16 * u + n][kc * 32 + 8 * q4];
#pragma unroll
            for (int m = 0; m < 2; ++m)
#pragma unroll
                for (int u = 0; u < 4; ++u)
                    acc[m][u] = __builtin_amdgcn_mfma_f32_16x16x32_bf16(
                        af[m], bfr[u], acc[m][u], 0, 0, 0);
        }
        __syncthreads();
    }

#pragma unroll
    for (int m = 0; m < 2; ++m) {
#pragma unroll
        for (int u = 0; u < 4; ++u) {
            const int col = n0 + 16 * u + n;
            const float bvv = bias[col];
#pragma unroll
            for (int r = 0; r < 4; ++r) {
                const int row = m0 + 32 * w + 16 * m + 4 * q4 + r;
                outF[(size_t)row * D_ + col] = acc[m][u][r] + bvv;
            }
        }
    }
}

// ---------------------------------------------------------------------------
// MFMA flash attention (byte-identical to r12, passing @ 68 us).
// ---------------------------------------------------------------------------
__global__ __launch_bounds__(256) void fattn_kernel(
    const bf16_t* __restrict__ qbh, const bf16_t* __restrict__ kbh,
    const bf16_t* __restrict__ vtb, const bf16_t* __restrict__ Eb,
    bf16_t* __restrict__ ctx) {
    __shared__ __align__(16) char smem[33792];
    float (*Om)[32][64] = (float(*)[32][64])smem;
    float (*ml)[32][2]  = (float(*)[32][2])(smem + 32768);

    const int tid = threadIdx.x;
    const int w = tid >> 6;
    const int lane = tid & 63;
    const int q4 = lane >> 4;
    const int n = lane & 15;
    const int bh = blockIdx.y;
    const int b = bh >> 4;
    const int h = bh & 15;
    const int ib = blockIdx.x * 32;

    bf16_t* band = (bf16_t*)smem + (size_t)w * (96 * 40);
    bf16_t* ps = band;   // aliased: band dead after skew-add, P stride 72

    bf16x8 ones;
#pragma unroll
    for (int e = 0; e < 8; ++e) ones[e] = (bf16_t)1.0f;

    bf16x8 aq[2][2];
#pragma unroll
    for (int m = 0; m < 2; ++m) {
        const bf16x8* qrow =
            (const bf16x8*)(qbh + ((size_t)bh * L_ + ib + 16 * m + n) * HD_);
        aq[m][0] = qrow[q4];
        aq[m][1] = qrow[4 + q4];
    }

    const bf16_t* vbase = vtb + (size_t)bh * HD_ * L_;

    f32x4 o[2][4] = {};
    float m_r[2][4], l_r[2][4];
#pragma unroll
    for (int m = 0; m < 2; ++m)
#pragma unroll
        for (int r = 0; r < 4; ++r) { m_r[m][r] = -1e30f; l_r[m][r] = 0.f; }

    for (int t = 0; t < 4; ++t) {
        const int j0 = w * 256 + t * 64;

        bf16x8 bk[4][2];
#pragma unroll
        for (int u = 0; u < 4; ++u)
#pragma unroll
            for (int kc = 0; kc < 2; ++kc)
                bk[u][kc] = *(const bf16x8*)(kbh +
                    ((size_t)bh * L_ + j0 + 16 * u + n) * HD_ + kc * 32 + 8 * q4);

        const int rbase = j0 - ib + 992;
#pragma unroll
        for (int up = 0; up < 6; ++up) {
            f32x4 rc[2] = {};
#pragma unroll
            for (int kc = 0; kc < 2; ++kc) {
                const bf16x8 be = *(const bf16x8*)(Eb +
                    ((size_t)(rbase + 16 * up + n)) * HD_ + kc * 32 + 8 * q4);
#pragma unroll
                for (int m = 0; m < 2; ++m)
                    rc[m] = __builtin_amdgcn_mfma_f32_16x16x32_bf16(
                        aq[m][kc], be, rc[m], 0, 0, 0);
            }
#pragma unroll
            for (int m = 0; m < 2; ++m) {
                bf16x4 pk;
#pragma unroll
                for (int r = 0; r < 4; ++r) pk[r] = (bf16_t)rc[m][r];
                *(bf16x4*)&band[(size_t)(16 * up + n) * 40 + 16 * m + 4 * q4] = pk;
            }
        }

        f32x4 s[2][4] = {};
#pragma unroll
        for (int u = 0; u < 4; ++u)
#pragma unroll
            for (int kc = 0; kc < 2; ++kc)
#pragma unroll
                for (int m = 0; m < 2; ++m)
                    s[m][u] = __builtin_amdgcn_mfma_f32_16x16x32_bf16(
                        aq[m][kc], bk[u][kc], s[m][u], 0, 0, 0);

        bf16x8 vf[4][2];
#pragma unroll
        for (int u = 0; u < 4; ++u)
#pragma unroll
            for (int kc = 0; kc < 2; ++kc)
                vf[u][kc] = *(const bf16x8*)(vbase +
                    ((size_t)(16 * u + n)) * L_ + j0 + kc * 32 + 8 * q4);

#pragma unroll
        for (int m = 0; m < 2; ++m)
#pragma unroll
            for (int u = 0; u < 4; ++u)
#pragma unroll
                for (int r = 0; r < 4; ++r) {
                    const int row = 16 * m + 4 * q4 + r;
                    s[m][u][r] +=
                        (float)band[(size_t)(16 * u + n - row + 31) * 40 + row];
                }

        float al[2][4];
#pragma unroll
        for (int m = 0; m < 2; ++m) {
#pragma unroll
            for (int r = 0; r < 4; ++r) {
                float mt = fmaxf(fmaxf(s[m][0][r], s[m][1][r]),
                                 fmaxf(s[m][2][r], s[m][3][r]));
                mt = dpp_fmax<0x121>(mt);
                mt = dpp_fmax<0x122>(mt);
                mt = dpp_fmax<0x124>(mt);
                mt = dpp_fmax<0x128>(mt);
                const float mn = fmaxf(m_r[m][r], mt);
                al[m][r] = __expf(m_r[m][r] - mn);
                m_r[m][r] = mn;
#pragma unroll
                for (int u = 0; u < 4; ++u) {
                    s[m][u][r] = __expf(s[m][u][r] - mn);
                    o[m][u][r] *= al[m][r];
                }
            }
        }

#pragma unroll
        for (int m = 0; m < 2; ++m)
#pragma unroll
            for (int u = 0; u < 4; ++u)
#pragma unroll
                for (int r = 0; r < 4; ++r)
                    ps[(size_t)(16 * m + 4 * q4 + r) * 72 + 16 * u + n] =
                        (bf16_t)s[m][u][r];

        bf16x8 pa[2][2];
#pragma unroll
        for (int m = 0; m < 2; ++m) {
            pa[m][0] = *(const bf16x8*)&ps[(size_t)(16 * m + n) * 72 + 8 * q4];
            pa[m][1] = *(const bf16x8*)&ps[(size_t)(16 * m + n) * 72 + 32 + 8 * q4];
        }

#pragma unroll
        for (int m = 0; m < 2; ++m) {
            f32x4 zz = {};
            zz = __builtin_amdgcn_mfma_f32_16x16x32_bf16(pa[m][0], ones, zz, 0, 0, 0);
            zz = __builtin_amdgcn_mfma_f32_16x16x32_bf16(pa[m][1], ones, zz, 0, 0, 0);
#pragma unroll
            for (int r = 0; r < 4; ++r)
                l_r[m][r] = l_r[m][r] * al[m][r] + zz[r];
        }

#pragma unroll
        for (int u = 0; u < 4; ++u)
#pragma unroll
            for (int kc = 0; kc < 2; ++kc)
#pragma unroll
                for (int m = 0; m < 2; ++m)
                    o[m][u] = __builtin_amdgcn_mfma_f32_16x16x32_bf16(
                        pa[m][kc], vf[u][kc], o[m][u], 0, 0, 0);
    }

    __syncthreads();
#pragma unroll
    for (int m = 0; m < 2; ++m)
#pragma unroll
        for (int u = 0; u < 4; ++u)
#pragma unroll
            for (int r = 0; r < 4; ++r)
                Om[w][16 * m + 4 * q4 + r][16 * u + n] = o[m][u][r];
    if (n == 0) {
#pragma unroll
        for (int m = 0; m < 2; ++m)
#pragma unroll
            for (int r = 0; r < 4; ++r) {
                ml[w][16 * m + 4 * q4 + r][0] = m_r[m][r];
                ml[w][16 * m + 4 * q4 + r][1] = l_r[m][r];
            }
    }
    __syncthreads();

    {
        const int row = tid >> 3;
        const int c0 = (tid & 7) * 8;
        const float m0v = ml[0][row][0], m1v = ml[1][row][0];
        const float m2v = ml[2][row][0], m3v = ml[3][row][0];
        const float ms = fmaxf(fmaxf(m0v, m1v), fmaxf(m2v, m3v));
        const float a0 = __expf(m0v - ms), a1 = __expf(m1v - ms);
        const float a2 = __expf(m2v - ms), a3 = __expf(m3v - ms);
        const float inv = 1.f / (a0 * ml[0][row][1] + a1 * ml[1][row][1] +
                                 a2 * ml[2][row][1] + a3 * ml[3][row][1]);
        bf16_t* dst = ctx + ((size_t)(b * L_ + ib + row)) * D_ + h * HD_ + c0;
#pragma unroll
        for (int cc = 0; cc < 8; ++cc) {
            const int col = c0 + cc;
            const float val = (a0 * Om[0][row][col] + a1 * Om[1][row][col] +
                               a2 * Om[2][row][col] + a3 * Om[3][row][col]) * inv;
            dst[cc] = (bf16_t)val;
        }
    }
}

// ---------------------------------------------------------------------------
extern "C" void kernel_launch(void* const* d_in, const int* in_sizes, int n_in,
                              void* d_out, int out_size, void* d_ws,
                              size_t ws_size, hipStream_t stream) {
    const float* x   = (const float*)d_in[0];
    const float* Wq  = (const float*)d_in[1];
    const float* bq  = (const float*)d_in[2];
    const float* Wk  = (const float*)d_in[3];
    const float* bk  = (const float*)d_in[4];
    const float* Wv  = (const float*)d_in[5];
    const float* bv  = (const float*)d_in[6];
    const float* Wo  = (const float*)d_in[7];
    const float* bo  = (const float*)d_in[8];
    const float* E   = (const float*)d_in[9];
    float* out = (float*)d_out;   // fp32 per reference (validated round 5)

    char* ws = (char*)d_ws;
    const size_t MB = 1024u * 1024u;
    bf16_t* xb   = (bf16_t*)(ws);             // 4 MB
    bf16_t* Wqb  = (bf16_t*)(ws + 4 * MB);    // 2 MB
    bf16_t* Wkb  = (bf16_t*)(ws + 6 * MB);    // 2 MB
    bf16_t* Wvb  = (bf16_t*)(ws + 8 * MB);    // 2 MB
    bf16_t* Wob  = (bf16_t*)(ws + 10 * MB);   // 2 MB
    bf16_t* qbh  = (bf16_t*)(ws + 12 * MB);   // 4 MB (BH,L,64), pre-scaled
    bf16_t* kbh  = (bf16_t*)(ws + 16 * MB);   // 4 MB (BH,L,64)
    bf16_t* vtb  = (bf16_t*)(ws + 20 * MB);   // 4 MB (BH,64,L) transposed
    bf16_t* ctxb = (bf16_t*)(ws + 24 * MB);   // 4 MB (B,L,D)
    bf16_t* Eb   = (bf16_t*)(ws + 28 * MB);   // 0.25 MB (2048x64)

    prep_kernel<<<6656, 256, 0, stream>>>(x, Wq, Wk, Wv, Wo, E,
                                          xb, Wqb, Wkb, Wvb, Wob, Eb);

    dim3 gq(D_ / 64, (B_ * L_) / 128, 3);  // (16, 16, 3) = 768 blocks
    qkv_gemm_kernel<<<gq, 256, 0, stream>>>(xb, Wqb, Wkb, Wvb, bq, bk, bv,
                                            qbh, kbh, vtb);

    dim3 ga(L_ / 32, B_ * H_);  // 1024 blocks
    fattn_kernel<<<ga, 256, 0, stream>>>(qbh, kbh, vtb, Eb, ctxb);

    dim3 gg(D_ / 64, (B_ * L_) / 128);  // (16, 16) = 256 blocks
    out_gemm_kernel<<<gg, 256, 0, stream>>>(ctxb, Wob, bo, out);
}

// Round 15
// 218.947 us; speedup vs baseline: 1.3321x; 1.3321x over previous
//
#include <hip/hip_runtime.h>
#include <hip/hip_bf16.h>

typedef __bf16 bf16_t;
typedef __bf16 bf16x8 __attribute__((ext_vector_type(8)));
typedef __bf16 bf16x4 __attribute__((ext_vector_type(4)));
typedef float f32x4 __attribute__((ext_vector_type(4)));

#define B_ 2
#define L_ 1024
#define D_ 1024
#define H_ 16
#define HD_ 64

// DPP rotate-reduce helper: fmax with lane (i+N)%16 within each 16-lane row.
template <int CTRL>
static __device__ __forceinline__ float dpp_fmax(float v) {
    const int t = __builtin_amdgcn_update_dpp(0, __float_as_int(v), CTRL,
                                              0xF, 0xF, true);
    return fmaxf(v, __int_as_float(t));
}

// ---------------------------------------------------------------------------
// Fused prep: x-cast (blocks 0..2047), W casts (2048..6143), E shift+cast
// (6144..6655).  (r12, passing)
// ---------------------------------------------------------------------------
__global__ __launch_bounds__(256) void prep_kernel(
    const float* __restrict__ x,
    const float* __restrict__ Wq, const float* __restrict__ Wk,
    const float* __restrict__ Wv, const float* __restrict__ Wo,
    const float* __restrict__ E,
    bf16_t* __restrict__ xb,
    bf16_t* __restrict__ Wqb, bf16_t* __restrict__ Wkb,
    bf16_t* __restrict__ Wvb, bf16_t* __restrict__ Wob,
    bf16_t* __restrict__ Eb) {
    const int bid = blockIdx.x;
    if (bid < 6144) {
        const float* src;
        bf16_t* dst;
        int i;
        if (bid < 2048) {
            src = x; dst = xb; i = bid * 256 + threadIdx.x;
        } else {
            const int z = (bid - 2048) >> 10;
            src = (z == 0) ? Wq : (z == 1) ? Wk : (z == 2) ? Wv : Wo;
            dst = (z == 0) ? Wqb : (z == 1) ? Wkb : (z == 2) ? Wvb : Wob;
            i = ((bid - 2048) & 1023) * 256 + threadIdx.x;
        }
        const float4 v = ((const float4*)src)[i];
        bf16x4 o;
        o[0] = (bf16_t)v.x; o[1] = (bf16_t)v.y;
        o[2] = (bf16_t)v.z; o[3] = (bf16_t)v.w;
        ((bf16x4*)dst)[i] = o;
    } else {
        const int idx = (bid - 6144) * 256 + threadIdx.x;
        if (idx < 64) Eb[idx] = (bf16_t)0.f;
        if (idx < 2047 * 64) Eb[64 + idx] = (bf16_t)E[idx];
    }
}

// ---------------------------------------------------------------------------
// Fused QKV GEMM — r12's 64x64 version, REVERTED verbatim (proven no-spill).
// 128x64 attempts (r13/r14) spilled acc to scratch (VGPR capped 44-48,
// WRITE_SIZE 8 MB -> 295 MB): launch_bounds' min-waves arg is only a
// ceiling, not a budget pin.
// ---------------------------------------------------------------------------
__global__ __launch_bounds__(256) void qkv_gemm_kernel(
    const bf16_t* __restrict__ xb,
    const bf16_t* __restrict__ Wqb, const bf16_t* __restrict__ Wkb,
    const bf16_t* __restrict__ Wvb,
    const float* __restrict__ bq, const float* __restrict__ bk2,
    const float* __restrict__ bv2,
    bf16_t* __restrict__ qbh, bf16_t* __restrict__ kbh,
    bf16_t* __restrict__ vtb) {
    constexpr int K = D_;
    __shared__ __align__(16) bf16_t As[64][72];
    __shared__ __align__(16) bf16_t Bs[64][72];

    const int z = blockIdx.z;
    const bf16_t* W = (z == 0) ? Wqb : (z == 1) ? Wkb : Wvb;
    const float* bias = (z == 0) ? bq : (z == 1) ? bk2 : bv2;
    const float alpha = (z == 0) ? 0.125f : 1.0f;

    const int tid = threadIdx.x;
    const int m0 = blockIdx.y * 64;
    const int n0 = blockIdx.x * 64;
    const int wave = tid >> 6;
    const int lane = tid & 63;
    const int wm = (wave >> 1) << 5;
    const int wn = (wave & 1) << 5;
    const int lrow = lane & 15;
    const int quad = lane >> 4;
    const int r0 = tid >> 3;
    const int c8 = (tid & 7) << 3;

    f32x4 acc[2][2] = {};

    uint4 pA0 = *(const uint4*)&xb[(size_t)(m0 + r0) * K + c8];
    uint4 pA1 = *(const uint4*)&xb[(size_t)(m0 + r0 + 32) * K + c8];
    uint4 pB0 = *(const uint4*)&W[(size_t)(n0 + r0) * K + c8];
    uint4 pB1 = *(const uint4*)&W[(size_t)(n0 + r0 + 32) * K + c8];

    for (int k0 = 0; k0 < K; k0 += 64) {
        *(uint4*)&As[r0][c8] = pA0;
        *(uint4*)&As[r0 + 32][c8] = pA1;
        *(uint4*)&Bs[r0][c8] = pB0;
        *(uint4*)&Bs[r0 + 32][c8] = pB1;
        const int kn = (k0 + 64 < K) ? k0 + 64 : k0;
        pA0 = *(const uint4*)&xb[(size_t)(m0 + r0) * K + kn + c8];
        pA1 = *(const uint4*)&xb[(size_t)(m0 + r0 + 32) * K + kn + c8];
        pB0 = *(const uint4*)&W[(size_t)(n0 + r0) * K + kn + c8];
        pB1 = *(const uint4*)&W[(size_t)(n0 + r0 + 32) * K + kn + c8];
        __syncthreads();

#pragma unroll
        for (int kc = 0; kc < 2; ++kc) {
            bf16x8 af[2], bfr[2];
            af[0]  = *(const bf16x8*)&As[wm + lrow][kc * 32 + 8 * quad];
            af[1]  = *(const bf16x8*)&As[wm + 16 + lrow][kc * 32 + 8 * quad];
            bfr[0] = *(const bf16x8*)&Bs[wn + lrow][kc * 32 + 8 * quad];
            bfr[1] = *(const bf16x8*)&Bs[wn + 16 + lrow][kc * 32 + 8 * quad];
#pragma unroll
            for (int t = 0; t < 2; ++t)
#pragma unroll
                for (int u = 0; u < 2; ++u)
                    acc[t][u] = __builtin_amdgcn_mfma_f32_16x16x32_bf16(
                        af[t], bfr[u], acc[t][u], 0, 0, 0);
        }
        __syncthreads();
    }

#pragma unroll
    for (int t = 0; t < 2; ++t) {
#pragma unroll
        for (int u = 0; u < 2; ++u) {
            const int col = n0 + wn + u * 16 + lrow;
            const float bvv = bias[col];
            const int h = col >> 6, d = col & 63;
            if (z < 2) {
                bf16_t* outp = z ? kbh : qbh;
#pragma unroll
                for (int r = 0; r < 4; ++r) {
                    const int row = m0 + wm + t * 16 + quad * 4 + r;
                    const int b = row >> 10, i = row & 1023;
                    outp[((size_t)((b * H_ + h) * L_ + i)) * HD_ + d] =
                        (bf16_t)((acc[t][u][r] + bvv) * alpha);
                }
            } else {
                const int row0 = m0 + wm + t * 16 + quad * 4;
                const int b = row0 >> 10, i = row0 & 1023;
                bf16x4 pk;
#pragma unroll
                for (int r = 0; r < 4; ++r) pk[r] = (bf16_t)(acc[t][u][r] + bvv);
                *(bf16x4*)&vtb[((size_t)((b * H_ + h) * HD_ + d)) * L_ + i] = pk;
            }
        }
    }
}

// ---------------------------------------------------------------------------
// Wo GEMM, 128x64 tile — EXPERIMENT: amdgpu_waves_per_eu(2,2) pins the
// register budget to 512/2 = 256 (min AND max), so the allocator cannot
// spill to chase occupancy. Bounded risk: out_gemm is only 256 blocks.
// ---------------------------------------------------------------------------
__global__
__attribute__((amdgpu_flat_work_group_size(256, 256)))
__attribute__((amdgpu_waves_per_eu(2, 2)))
void out_gemm_kernel(
    const bf16_t* __restrict__ A, const bf16_t* __restrict__ W,
    const float* __restrict__ bias, float* __restrict__ outF) {
    constexpr int K = D_;
    __shared__ __align__(16) bf16_t As[128][72];
    __shared__ __align__(16) bf16_t Bs[64][72];

    const int tid = threadIdx.x;
    const int m0 = blockIdx.y * 128;
    const int n0 = blockIdx.x * 64;
    const int w = tid >> 6;
    const int lane = tid & 63;
    const int n = lane & 15;
    const int q4 = lane >> 4;
    const int r0 = tid >> 3;
    const int c8 = (tid & 7) << 3;

    f32x4 acc[2][4] = {};

    uint4 pA[4], pB[2];
#pragma unroll
    for (int i = 0; i < 4; ++i)
        pA[i] = *(const uint4*)&A[(size_t)(m0 + r0 + 32 * i) * K + c8];
#pragma unroll
    for (int i = 0; i < 2; ++i)
        pB[i] = *(const uint4*)&W[(size_t)(n0 + r0 + 32 * i) * K + c8];

    for (int k0 = 0; k0 < K; k0 += 64) {
#pragma unroll
        for (int i = 0; i < 4; ++i) *(uint4*)&As[r0 + 32 * i][c8] = pA[i];
#pragma unroll
        for (int i = 0; i < 2; ++i) *(uint4*)&Bs[r0 + 32 * i][c8] = pB[i];
        const int kn = (k0 + 64 < K) ? k0 + 64 : k0;
#pragma unroll
        for (int i = 0; i < 4; ++i)
            pA[i] = *(const uint4*)&A[(size_t)(m0 + r0 + 32 * i) * K + kn + c8];
#pragma unroll
        for (int i = 0; i < 2; ++i)
            pB[i] = *(const uint4*)&W[(size_t)(n0 + r0 + 32 * i) * K + kn + c8];
        __syncthreads();

#pragma unroll
        for (int kc = 0; kc < 2; ++kc) {
            bf16x8 af[2], bfr[4];
#pragma unroll
            for (int m = 0; m < 2; ++m)
                af[m] = *(const bf16x8*)&As[w * 32 + 16 * m + n][kc * 32 + 8 * q4];
#pragma unroll
            for (int u = 0; u < 4; ++u)
                bfr[u] = *(const bf16x8*)&Bs[16 * u + n][kc * 32 + 8 * q4];
#pragma unroll
            for (int m = 0; m < 2; ++m)
#pragma unroll
                for (int u = 0; u < 4; ++u)
                    acc[m][u] = __builtin_amdgcn_mfma_f32_16x16x32_bf16(
                        af[m], bfr[u], acc[m][u], 0, 0, 0);
        }
        __syncthreads();
    }

#pragma unroll
    for (int m = 0; m < 2; ++m) {
#pragma unroll
        for (int u = 0; u < 4; ++u) {
            const int col = n0 + 16 * u + n;
            const float bvv = bias[col];
#pragma unroll
            for (int r = 0; r < 4; ++r) {
                const int row = m0 + 32 * w + 16 * m + 4 * q4 + r;
                outF[(size_t)row * D_ + col] = acc[m][u][r] + bvv;
            }
        }
    }
}

// ---------------------------------------------------------------------------
// MFMA flash attention (byte-identical to r12, passing @ 68 us).
// ---------------------------------------------------------------------------
__global__ __launch_bounds__(256) void fattn_kernel(
    const bf16_t* __restrict__ qbh, const bf16_t* __restrict__ kbh,
    const bf16_t* __restrict__ vtb, const bf16_t* __restrict__ Eb,
    bf16_t* __restrict__ ctx) {
    __shared__ __align__(16) char smem[33792];
    float (*Om)[32][64] = (float(*)[32][64])smem;
    float (*ml)[32][2]  = (float(*)[32][2])(smem + 32768);

    const int tid = threadIdx.x;
    const int w = tid >> 6;
    const int lane = tid & 63;
    const int q4 = lane >> 4;
    const int n = lane & 15;
    const int bh = blockIdx.y;
    const int b = bh >> 4;
    const int h = bh & 15;
    const int ib = blockIdx.x * 32;

    bf16_t* band = (bf16_t*)smem + (size_t)w * (96 * 40);
    bf16_t* ps = band;   // aliased: band dead after skew-add, P stride 72

    bf16x8 ones;
#pragma unroll
    for (int e = 0; e < 8; ++e) ones[e] = (bf16_t)1.0f;

    bf16x8 aq[2][2];
#pragma unroll
    for (int m = 0; m < 2; ++m) {
        const bf16x8* qrow =
            (const bf16x8*)(qbh + ((size_t)bh * L_ + ib + 16 * m + n) * HD_);
        aq[m][0] = qrow[q4];
        aq[m][1] = qrow[4 + q4];
    }

    const bf16_t* vbase = vtb + (size_t)bh * HD_ * L_;

    f32x4 o[2][4] = {};
    float m_r[2][4], l_r[2][4];
#pragma unroll
    for (int m = 0; m < 2; ++m)
#pragma unroll
        for (int r = 0; r < 4; ++r) { m_r[m][r] = -1e30f; l_r[m][r] = 0.f; }

    for (int t = 0; t < 4; ++t) {
        const int j0 = w * 256 + t * 64;

        bf16x8 bk[4][2];
#pragma unroll
        for (int u = 0; u < 4; ++u)
#pragma unroll
            for (int kc = 0; kc < 2; ++kc)
                bk[u][kc] = *(const bf16x8*)(kbh +
                    ((size_t)bh * L_ + j0 + 16 * u + n) * HD_ + kc * 32 + 8 * q4);

        const int rbase = j0 - ib + 992;
#pragma unroll
        for (int up = 0; up < 6; ++up) {
            f32x4 rc[2] = {};
#pragma unroll
            for (int kc = 0; kc < 2; ++kc) {
                const bf16x8 be = *(const bf16x8*)(Eb +
                    ((size_t)(rbase + 16 * up + n)) * HD_ + kc * 32 + 8 * q4);
#pragma unroll
                for (int m = 0; m < 2; ++m)
                    rc[m] = __builtin_amdgcn_mfma_f32_16x16x32_bf16(
                        aq[m][kc], be, rc[m], 0, 0, 0);
            }
#pragma unroll
            for (int m = 0; m < 2; ++m) {
                bf16x4 pk;
#pragma unroll
                for (int r = 0; r < 4; ++r) pk[r] = (bf16_t)rc[m][r];
                *(bf16x4*)&band[(size_t)(16 * up + n) * 40 + 16 * m + 4 * q4] = pk;
            }
        }

        f32x4 s[2][4] = {};
#pragma unroll
        for (int u = 0; u < 4; ++u)
#pragma unroll
            for (int kc = 0; kc < 2; ++kc)
#pragma unroll
                for (int m = 0; m < 2; ++m)
                    s[m][u] = __builtin_amdgcn_mfma_f32_16x16x32_bf16(
                        aq[m][kc], bk[u][kc], s[m][u], 0, 0, 0);

        bf16x8 vf[4][2];
#pragma unroll
        for (int u = 0; u < 4; ++u)
#pragma unroll
            for (int kc = 0; kc < 2; ++kc)
                vf[u][kc] = *(const bf16x8*)(vbase +
                    ((size_t)(16 * u + n)) * L_ + j0 + kc * 32 + 8 * q4);

#pragma unroll
        for (int m = 0; m < 2; ++m)
#pragma unroll
            for (int u = 0; u < 4; ++u)
#pragma unroll
                for (int r = 0; r < 4; ++r) {
                    const int row = 16 * m + 4 * q4 + r;
                    s[m][u][r] +=
                        (float)band[(size_t)(16 * u + n - row + 31) * 40 + row];
                }

        float al[2][4];
#pragma unroll
        for (int m = 0; m < 2; ++m) {
#pragma unroll
            for (int r = 0; r < 4; ++r) {
                float mt = fmaxf(fmaxf(s[m][0][r], s[m][1][r]),
                                 fmaxf(s[m][2][r], s[m][3][r]));
                mt = dpp_fmax<0x121>(mt);
                mt = dpp_fmax<0x122>(mt);
                mt = dpp_fmax<0x124>(mt);
                mt = dpp_fmax<0x128>(mt);
                const float mn = fmaxf(m_r[m][r], mt);
                al[m][r] = __expf(m_r[m][r] - mn);
                m_r[m][r] = mn;
#pragma unroll
                for (int u = 0; u < 4; ++u) {
                    s[m][u][r] = __expf(s[m][u][r] - mn);
                    o[m][u][r] *= al[m][r];
                }
            }
        }

#pragma unroll
        for (int m = 0; m < 2; ++m)
#pragma unroll
            for (int u = 0; u < 4; ++u)
#pragma unroll
                for (int r = 0; r < 4; ++r)
                    ps[(size_t)(16 * m + 4 * q4 + r) * 72 + 16 * u + n] =
                        (bf16_t)s[m][u][r];

        bf16x8 pa[2][2];
#pragma unroll
        for (int m = 0; m < 2; ++m) {
            pa[m][0] = *(const bf16x8*)&ps[(size_t)(16 * m + n) * 72 + 8 * q4];
            pa[m][1] = *(const bf16x8*)&ps[(size_t)(16 * m + n) * 72 + 32 + 8 * q4];
        }

#pragma unroll
        for (int m = 0; m < 2; ++m) {
            f32x4 zz = {};
            zz = __builtin_amdgcn_mfma_f32_16x16x32_bf16(pa[m][0], ones, zz, 0, 0, 0);
            zz = __builtin_amdgcn_mfma_f32_16x16x32_bf16(pa[m][1], ones, zz, 0, 0, 0);
#pragma unroll
            for (int r = 0; r < 4; ++r)
                l_r[m][r] = l_r[m][r] * al[m][r] + zz[r];
        }

#pragma unroll
        for (int u = 0; u < 4; ++u)
#pragma unroll
            for (int kc = 0; kc < 2; ++kc)
#pragma unroll
                for (int m = 0; m < 2; ++m)
                    o[m][u] = __builtin_amdgcn_mfma_f32_16x16x32_bf16(
                        pa[m][kc], vf[u][kc], o[m][u], 0, 0, 0);
    }

    __syncthreads();
#pragma unroll
    for (int m = 0; m < 2; ++m)
#pragma unroll
        for (int u = 0; u < 4; ++u)
#pragma unroll
            for (int r = 0; r < 4; ++r)
                Om[w][16 * m + 4 * q4 + r][16 * u + n] = o[m][u][r];
    if (n == 0) {
#pragma unroll
        for (int m = 0; m < 2; ++m)
#pragma unroll
            for (int r = 0; r < 4; ++r) {
                ml[w][16 * m + 4 * q4 + r][0] = m_r[m][r];
                ml[w][16 * m + 4 * q4 + r][1] = l_r[m][r];
            }
    }
    __syncthreads();

    {
        const int row = tid >> 3;
        const int c0 = (tid & 7) * 8;
        const float m0v = ml[0][row][0], m1v = ml[1][row][0];
        const float m2v = ml[2][row][0], m3v = ml[3][row][0];
        const float ms = fmaxf(fmaxf(m0v, m1v), fmaxf(m2v, m3v));
        const float a0 = __expf(m0v - ms), a1 = __expf(m1v - ms);
        const float a2 = __expf(m2v - ms), a3 = __expf(m3v - ms);
        const float inv = 1.f / (a0 * ml[0][row][1] + a1 * ml[1][row][1] +
                                 a2 * ml[2][row][1] + a3 * ml[3][row][1]);
        bf16_t* dst = ctx + ((size_t)(b * L_ + ib + row)) * D_ + h * HD_ + c0;
#pragma unroll
        for (int cc = 0; cc < 8; ++cc) {
            const int col = c0 + cc;
            const float val = (a0 * Om[0][row][col] + a1 * Om[1][row][col] +
                               a2 * Om[2][row][col] + a3 * Om[3][row][col]) * inv;
            dst[cc] = (bf16_t)val;
        }
    }
}

// ---------------------------------------------------------------------------
extern "C" void kernel_launch(void* const* d_in, const int* in_sizes, int n_in,
                              void* d_out, int out_size, void* d_ws,
                              size_t ws_size, hipStream_t stream) {
    const float* x   = (const float*)d_in[0];
    const float* Wq  = (const float*)d_in[1];
    const float* bq  = (const float*)d_in[2];
    const float* Wk  = (const float*)d_in[3];
    const float* bk  = (const float*)d_in[4];
    const float* Wv  = (const float*)d_in[5];
    const float* bv  = (const float*)d_in[6];
    const float* Wo  = (const float*)d_in[7];
    const float* bo  = (const float*)d_in[8];
    const float* E   = (const float*)d_in[9];
    float* out = (float*)d_out;   // fp32 per reference (validated round 5)

    char* ws = (char*)d_ws;
    const size_t MB = 1024u * 1024u;
    bf16_t* xb   = (bf16_t*)(ws);             // 4 MB
    bf16_t* Wqb  = (bf16_t*)(ws + 4 * MB);    // 2 MB
    bf16_t* Wkb  = (bf16_t*)(ws + 6 * MB);    // 2 MB
    bf16_t* Wvb  = (bf16_t*)(ws + 8 * MB);    // 2 MB
    bf16_t* Wob  = (bf16_t*)(ws + 10 * MB);   // 2 MB
    bf16_t* qbh  = (bf16_t*)(ws + 12 * MB);   // 4 MB (BH,L,64), pre-scaled
    bf16_t* kbh  = (bf16_t*)(ws + 16 * MB);   // 4 MB (BH,L,64)
    bf16_t* vtb  = (bf16_t*)(ws + 20 * MB);   // 4 MB (BH,64,L) transposed
    bf16_t* ctxb = (bf16_t*)(ws + 24 * MB);   // 4 MB (B,L,D)
    bf16_t* Eb   = (bf16_t*)(ws + 28 * MB);   // 0.25 MB (2048x64)

    prep_kernel<<<6656, 256, 0, stream>>>(x, Wq, Wk, Wv, Wo, E,
                                          xb, Wqb, Wkb, Wvb, Wob, Eb);

    dim3 gq(D_ / 64, (B_ * L_) / 64, 3);  // 1536 blocks (r12 config)
    qkv_gemm_kernel<<<gq, 256, 0, stream>>>(xb, Wqb, Wkb, Wvb, bq, bk, bv,
                                            qbh, kbh, vtb);

    dim3 ga(L_ / 32, B_ * H_);  // 1024 blocks
    fattn_kernel<<<ga, 256, 0, stream>>>(qbh, kbh, vtb, Eb, ctxb);

    dim3 gg(D_ / 64, (B_ * L_) / 128);  // (16, 16) = 256 blocks
    out_gemm_kernel<<<gg, 256, 0, stream>>>(ctxb, Wob, bo, out);
}